// Round 20
// baseline (170.684 us; speedup 1.0000x reference)
//
#include <hip/hip_runtime.h>
#include <math.h>

#define BB 8
#define LL 2048
#define MM 4096
#define DD 512
#define NQ (BB*LL)           // 16384 query rows
#define NM (BB*MM)           // 32768 memory rows
#define TOPK 5
#define TOPS 8               // kept per (row, split)
#define MSPLIT 2
#define NC (MSPLIT*TOPS)     // 16 candidates per row
#define MRANGE (MM/MSPLIT)   // 2048

// rescue-set margin: ~10 sigma of (bf16-dot noise + 11-bit key quant); see R19 notes.
#define EPS_KEY 0.02f

// ws layout (4-byte units): RM (NM f32) | CK (NQ*NC u32 packed keys) | ENCP (NQ*DD bf16)
#define WS_RM 0
#define WS_CK (WS_RM + NM)
#define WS_ENCP (WS_CK + NQ*NC)

typedef short bf16x8 __attribute__((ext_vector_type(8)));
typedef float f32x16 __attribute__((ext_vector_type(16)));

__device__ __forceinline__ ushort f2bf(float f) {
  unsigned u = __builtin_bit_cast(unsigned, f);
  unsigned r = u + 0x7FFFu + ((u >> 16) & 1u);   // RNE
  return (ushort)(r >> 16);
}

// single-instruction 3-input median (sorted-insert workhorse)
__device__ __forceinline__ unsigned med3u(unsigned a, unsigned b, unsigned c) {
  unsigned d;
  asm("v_med3_u32 %0, %1, %2, %3" : "=v"(d) : "v"(a), "v"(b), "v"(c));
  return d;
}

// key = (bits(v) & 0xFFFFF800) | idx  in ONE VOP3 (mask lives in an SGPR)
__device__ __forceinline__ unsigned mkkey(float v, unsigned idx) {
  unsigned d;
  asm("v_and_or_b32 %0, %1, %2, %3" : "=v"(d)
      : "v"(__builtin_bit_cast(unsigned, v)), "s"(0xFFFFF800u), "v"(idx));
  return d;
}

// sorted-desc top-5 insert via med3 identity: new[s] = med3(k, old[s-1], old[s]).
__device__ __forceinline__ void ins5(unsigned* bk, unsigned k) {
  bk[4] = med3u(k, bk[3], bk[4]);
  bk[3] = med3u(k, bk[2], bk[3]);
  bk[2] = med3u(k, bk[1], bk[2]);
  bk[1] = med3u(k, bk[0], bk[1]);
  bk[0] = (bk[0] > k) ? bk[0] : k;
}

#define CS(i, j) { const unsigned hi = (L[i] > L[j]) ? L[i] : L[j]; \
                   const unsigned lo = (L[i] > L[j]) ? L[j] : L[i]; \
                   L[i] = hi; L[j] = lo; }

// merge two sorted-desc 8-lists -> top-8 sorted desc (bitonic)
__device__ __forceinline__ void mrg8(unsigned* a, const unsigned* b) {
  unsigned L[8];
  #pragma unroll
  for (int i = 0; i < 8; ++i) L[i] = (a[i] > b[7 - i]) ? a[i] : b[7 - i];
  CS(0,4) CS(1,5) CS(2,6) CS(3,7)
  CS(0,2) CS(1,3) CS(4,6) CS(5,7)
  CS(0,1) CS(2,3) CS(4,5) CS(6,7)
  #pragma unroll
  for (int i = 0; i < 8; ++i) a[i] = L[i];
}

// ---------------- kernel 1: fused pack of enc (raw) + mem (normalized) ----------------
#define LDSW 516
__global__ __launch_bounds__(256) void k_prep2(const float* __restrict__ enc,
                                               const float* __restrict__ mem,
                                               ushort* __restrict__ encP,
                                               ushort* __restrict__ memP,
                                               float* __restrict__ rmOut) {
  __shared__ float st[32 * LDSW];
  __shared__ float rs_s[32];
  const int blk = blockIdx.x;
  const bool isenc = blk < (NQ / 32);
  const int tile = isenc ? blk : blk - NQ / 32;
  const float* src = isenc ? enc : mem;
  ushort* dstP = isenc ? encP : memP;
  const int tid = threadIdx.x;
  const float* sB = src + (size_t)tile * 32 * DD;

  #pragma unroll
  for (int i = 0; i < 16; ++i) {
    const int idx = tid + i * 256;
    const int row = idx >> 7, c4 = idx & 127;
    *(float4*)&st[row * LDSW + c4 * 4] = *(const float4*)&sB[(size_t)row * DD + c4 * 4];
  }
  __syncthreads();

  if (!isenc) {
    const int row = tid >> 3, seg = tid & 7;
    float ss = 0.0f;
    #pragma unroll
    for (int i = 0; i < 16; ++i) {
      const float4 x = *(const float4*)&st[row * LDSW + seg * 64 + i * 4];
      ss += x.x*x.x + x.y*x.y + x.z*x.z + x.w*x.w;
    }
    #pragma unroll
    for (int m = 1; m < 8; m <<= 1) ss += __shfl_xor(ss, m, 64);
    if (seg == 0) {
      const float rn = 1.0f / fmaxf(sqrtf(ss), 1e-12f);
      rs_s[row] = rn;
      rmOut[tile * 32 + row] = rn;
    }
    __syncthreads();
  }

  #pragma unroll
  for (int i = 0; i < 8; ++i) {
    const int slot = tid + i * 256;
    const int kt = slot >> 6, l = slot & 63;
    const int row = l & 31;
    const int k0 = kt * 16 + (l >> 5) * 8;
    const float sc = isenc ? 1.0f : rs_s[row];
    const float4 x0 = *(const float4*)&st[row * LDSW + k0];
    const float4 x1 = *(const float4*)&st[row * LDSW + k0 + 4];
    uint4 o;
    o.x = (unsigned)f2bf(x0.x * sc) | ((unsigned)f2bf(x0.y * sc) << 16);
    o.y = (unsigned)f2bf(x0.z * sc) | ((unsigned)f2bf(x0.w * sc) << 16);
    o.z = (unsigned)f2bf(x1.x * sc) | ((unsigned)f2bf(x1.y * sc) << 16);
    o.w = (unsigned)f2bf(x1.z * sc) | ((unsigned)f2bf(x1.w * sc) << 16);
    ((uint4*)dstP)[(size_t)tile * 2048 + slot] = o;
  }
}

// ---------------- kernel 2: 32x32x16 MFMA screen (R18/R19 body, verbatim) ----------------
__global__ __launch_bounds__(512, 4) void k_screen(const ushort* __restrict__ encP,
                                                   const ushort* __restrict__ memP,
                                                   unsigned* __restrict__ wsck) {
  __shared__ uint4 ebuf[4096];                   // 64 KB: 2 enc tiles; reused for merge lists
  unsigned* ml = (unsigned*)ebuf;
  const int tid = threadIdx.x;
  const int l = tid & 63;
  const int w = tid >> 6;                        // 0..7
  const int ord = blockIdx.x;
  const int x = ord & 7;                         // XCD id (round-robin dispatch heuristic)
  const int j = ord >> 3;                        // 0..63 within XCD
  const int qt = x * 32 + (j >> 1);              // qt in batch x  (qt>>5 == x)
  const int split = j & 1;
  const int qbase = qt * 64;
  const int atile0 = x * (MM / 32) + split * (MRANGE / 32);

  {
    const uint4* src = (const uint4*)encP + (size_t)(qt * 2) * 2048;
    #pragma unroll
    for (int i = 0; i < 8; ++i) ebuf[tid + i * 512] = src[tid + i * 512];
  }
  __syncthreads();

  unsigned tv[2][TOPS];
  #pragma unroll
  for (int qs = 0; qs < 2; ++qs)
    #pragma unroll
    for (int s = 0; s < TOPS; ++s) tv[qs][s] = 0u;

  #pragma unroll 1
  for (int t = 0; t < 4; ++t) {
    unsigned bk[2][5];
    #pragma unroll
    for (int qs = 0; qs < 2; ++qs)
      #pragma unroll
      for (int s = 0; s < 5; ++s) bk[qs][s] = 0u;

    f32x16 acc00 = (f32x16)(0.0f), acc01 = (f32x16)(0.0f);
    f32x16 acc10 = (f32x16)(0.0f), acc11 = (f32x16)(0.0f);
    const ushort* aT = memP + (size_t)(atile0 + t * 16 + w * 2) * 16384 + (size_t)l * 8;

    __builtin_amdgcn_s_setprio(1);
    #pragma unroll 2
    for (int kc = 0; kc < 32; ++kc) {
      const bf16x8 a0 = *(const bf16x8*)(aT + kc * 512);
      const bf16x8 a1 = *(const bf16x8*)(aT + 16384 + kc * 512);
      const bf16x8 b0 = *(const bf16x8*)&ebuf[kc * 64 + l];
      const bf16x8 b1 = *(const bf16x8*)&ebuf[2048 + kc * 64 + l];
      acc00 = __builtin_amdgcn_mfma_f32_32x32x16_bf16(a0, b0, acc00, 0, 0, 0);
      acc01 = __builtin_amdgcn_mfma_f32_32x32x16_bf16(a0, b1, acc01, 0, 0, 0);
      acc10 = __builtin_amdgcn_mfma_f32_32x32x16_bf16(a1, b0, acc10, 0, 0, 0);
      acc11 = __builtin_amdgcn_mfma_f32_32x32x16_bf16(a1, b1, acc11, 0, 0, 0);
    }
    __builtin_amdgcn_s_setprio(0);

    const unsigned ib0 = 2047u - (unsigned)(t * 512 + w * 64 + 4 * (l >> 5));
    #pragma unroll
    for (int r = 0; r < 16; ++r) {
      const unsigned idx = ib0 - (unsigned)((r & 3) + 8 * (r >> 2));
      ins5(bk[0], mkkey(acc00[r] + 28.0f, idx));
      ins5(bk[1], mkkey(acc01[r] + 28.0f, idx));
      ins5(bk[0], mkkey(acc10[r] + 28.0f, idx - 32u));
      ins5(bk[1], mkkey(acc11[r] + 28.0f, idx - 32u));
    }

    #pragma unroll
    for (int qs = 0; qs < 2; ++qs) {
      const unsigned bb[8] = {bk[qs][0], bk[qs][1], bk[qs][2], bk[qs][3], bk[qs][4],
                              0u, 0u, 0u};
      mrg8(tv[qs], bb);
    }
  }

  // merge lane-halves (l <-> l+32): both halves end with the full per-q list
  #pragma unroll
  for (int qs = 0; qs < 2; ++qs) {
    unsigned ov[TOPS];
    #pragma unroll
    for (int s = 0; s < TOPS; ++s) ov[s] = (unsigned)__shfl_xor((int)tv[qs][s], 32, 64);
    mrg8(tv[qs], ov);
  }

  __syncthreads();                               // all ebuf reads done; reuse LDS for lists
  if (w > 0 && l < 32) {
    #pragma unroll
    for (int qs = 0; qs < 2; ++qs)
      #pragma unroll
      for (int s = 0; s < TOPS; ++s)
        ml[((w - 1) * 64 + qs * 32 + l) * 8 + s] = tv[qs][s];
  }
  __syncthreads();
  if (w == 0) {
    #pragma unroll
    for (int pp = 0; pp < 7; ++pp) {
      #pragma unroll
      for (int qs = 0; qs < 2; ++qs) {
        unsigned ov[TOPS];
        #pragma unroll
        for (int s = 0; s < TOPS; ++s) ov[s] = ml[(pp * 64 + qs * 32 + (l & 31)) * 8 + s];
        mrg8(tv[qs], ov);
      }
    }
    if (l < 32) {
      #pragma unroll
      for (int qs = 0; qs < 2; ++qs) {
        const int q = qbase + qs * 32 + l;
        #pragma unroll
        for (int s = 0; s < TOPS; ++s)
          wsck[q * NC + split * TOPS + s] = tv[qs][s];   // packed key
      }
    }
  }
}

// ---------------- kernel 3: rescue-set rescore with BATCHED upfront gather ----------------
// Phase 2 rewrite: each wave issues ALL its candidate-row loads (j = w, w+4, w+8, w+12,
// guarded by wave-uniform j<T) before any butterfly -> up to 8 loads in flight vs 2.
__global__ __launch_bounds__(256) void k_out(const float* __restrict__ enc,
                                             const float* __restrict__ mem,
                                             const float* __restrict__ wsf,
                                             const unsigned* __restrict__ wsck,
                                             float* __restrict__ out) {
  __shared__ double sc_s[NC];
  __shared__ int cm_s[NC];
  __shared__ int lst_s[NC];
  __shared__ int T_s;
  __shared__ int sel_s[TOPK];
  const int ord = blockIdx.x;
  const int row = (ord & 7) * 2048 + (ord >> 3);   // bijective: XCD x <- batch x
  const int tid = threadIdx.x;
  const int lane = tid & 63;
  const int w = tid >> 6;
  const int b = row >> 11;
  const float* er = enc + (size_t)row * DD;
  const float* mb = mem + (size_t)b * MM * DD;

  // --- phase 1: build rescue list from packed keys (wave 0) ---
  if (w == 0) {
    const unsigned my = (lane < NC) ? wsck[row * NC + lane] : 0u;
    int rank = 0;
    #pragma unroll
    for (int e2 = 0; e2 < NC; ++e2) {
      const unsigned o = (unsigned)__shfl((int)my, e2, 64);
      rank += (o > my) ? 1 : 0;
    }
    unsigned c5 = (rank == 4) ? my : 0u;
    #pragma unroll
    for (int off = 1; off < 16; off <<= 1)
      c5 |= (unsigned)__shfl_xor((int)c5, off, 64);
    const float kf5 = __builtin_bit_cast(float, c5 & 0xFFFFF800u);
    const float kfm = __builtin_bit_cast(float, my & 0xFFFFF800u);
    const bool flag = (lane < NC) && (kfm >= kf5 - EPS_KEY);
    const unsigned long long bmask = __ballot(flag);
    const unsigned lowm = (unsigned)bmask & 0xFFFFu;
    if (flag) {
      const int pos = __popc(lowm & ((1u << lane) - 1u));
      const int split = lane >> 3;               // slots 0-7 split0, 8-15 split1
      lst_s[pos] = split * MRANGE + 2047 - (int)(my & 0x7FFu);
    }
    if (lane == 0) T_s = __popc(lowm);
    if (lane < NC) { sc_s[lane] = -1.0e300; cm_s[lane] = 0x7fff0000 + lane; }
  }
  __syncthreads();
  const int T = T_s;

  // --- phase 2: batched fp64 rescore of rescue set ---
  const int d0 = lane * 8;
  const float4 e0 = *(const float4*)(er + d0);
  const float4 e1 = *(const float4*)(er + d0 + 4);
  const double ed0 = e0.x, ed1 = e0.y, ed2 = e0.z, ed3 = e0.w;
  const double ed4 = e1.x, ed5 = e1.y, ed6 = e1.z, ed7 = e1.w;

  int cms[4];
  float4 X0[4], X1[4];
  #pragma unroll
  for (int ii = 0; ii < 4; ++ii) {               // issue ALL gathers upfront (uniform guards)
    const int jj = w + ii * 4;
    if (jj < T) {
      const int cm = lst_s[jj];
      cms[ii] = cm;
      const float* mr = mb + (size_t)cm * DD + d0;
      X0[ii] = *(const float4*)mr;
      X1[ii] = *(const float4*)(mr + 4);
    }
  }
  #pragma unroll
  for (int ii = 0; ii < 4; ++ii) {
    const int jj = w + ii * 4;
    if (jj < T) {
      double t = ed0 * (double)X0[ii].x;
      t = fma(ed1, (double)X0[ii].y, t); t = fma(ed2, (double)X0[ii].z, t);
      t = fma(ed3, (double)X0[ii].w, t); t = fma(ed4, (double)X1[ii].x, t);
      t = fma(ed5, (double)X1[ii].y, t); t = fma(ed6, (double)X1[ii].z, t);
      t = fma(ed7, (double)X1[ii].w, t);
      #pragma unroll
      for (int off = 1; off < 64; off <<= 1) t += __shfl_xor(t, off, 64);
      if (lane == 0) {
        sc_s[jj] = t * (double)wsf[WS_RM + b * MM + cms[ii]];
        cm_s[jj] = cms[ii];
      }
    }
  }
  __syncthreads();

  // --- phase 3: wave 0 ranks rescued scores by (value desc, index asc) ---
  if (w == 0) {
    const int e = lane & 15;
    const double mk = sc_s[e];
    const int mi = cm_s[e];
    int rank = 0;
    #pragma unroll
    for (int e2 = 0; e2 < NC; ++e2) {
      const double k2 = sc_s[e2];
      const int i2 = cm_s[e2];
      rank += ((k2 > mk) || (k2 == mk && i2 < mi)) ? 1 : 0;
    }
    if (lane < NC && rank < TOPK) sel_s[rank] = mi;
  }
  __syncthreads();

  // --- phase 4: gather + mean + add (2 dims/thread) ---
  const int sel0 = sel_s[0], sel1 = sel_s[1], sel2 = sel_s[2],
            sel3 = sel_s[3], sel4 = sel_s[4];
  const int d = tid * 2;
  const float2 ev = *(const float2*)(er + d);
  const float2 x0 = *(const float2*)(mb + (size_t)sel0 * DD + d);
  const float2 x1 = *(const float2*)(mb + (size_t)sel1 * DD + d);
  const float2 x2 = *(const float2*)(mb + (size_t)sel2 * DD + d);
  const float2 x3 = *(const float2*)(mb + (size_t)sel3 * DD + d);
  const float2 x4 = *(const float2*)(mb + (size_t)sel4 * DD + d);
  float2 o;
  o.x = ev.x + (x0.x + x1.x + x2.x + x3.x + x4.x) / 5.0f;
  o.y = ev.y + (x0.y + x1.y + x2.y + x3.y + x4.y) / 5.0f;
  *(float2*)(out + (size_t)row * DD + d) = o;
}

extern "C" void kernel_launch(void* const* d_in, const int* in_sizes, int n_in,
                              void* d_out, int out_size, void* d_ws, size_t ws_size,
                              hipStream_t stream) {
  (void)in_sizes; (void)n_in; (void)out_size; (void)ws_size;
  const float* enc = (const float*)d_in[0];
  const float* mem = (const float*)d_in[1];
  float* out = (float*)d_out;
  float* wsf = (float*)d_ws;
  unsigned* wsck = (unsigned*)d_ws + WS_CK;
  ushort* encP = (ushort*)(wsf + WS_ENCP);
  ushort* memP = (ushort*)d_out;   // NM*DD bf16 == out bytes exactly; k_out overwrites

  // 1) fused pack: enc (raw) + mem (row-normalized) into 32x32x16 MFMA operand layout
  k_prep2<<<dim3(NQ / 32 + NM / 32), dim3(256), 0, stream>>>(enc, mem, encP, memP,
                                                             wsf + WS_RM);

  // 2) MFMA screening: per (row, M/2-split) top-8 packed keys (batch-per-XCD mapping)
  k_screen<<<dim3(512), dim3(512), 0, stream>>>(encP, memP, wsck);

  // 3) certified rescue-set fp64 rescore (batched gather), exact top-5, gather, mean, add
  k_out<<<dim3(NQ), dim3(256), 0, stream>>>(enc, mem, wsf, wsck, out);
}

// Round 21
// 156.535 us; speedup vs baseline: 1.0904x; 1.0904x over previous
//
#include <hip/hip_runtime.h>
#include <math.h>

#define BB 8
#define LL 2048
#define MM 4096
#define DD 512
#define NQ (BB*LL)           // 16384 query rows
#define NM (BB*MM)           // 32768 memory rows
#define TOPK 5
#define TOPS 8               // kept per (row, split)
#define MSPLIT 2
#define NC (MSPLIT*TOPS)     // 16 candidates per row
#define MRANGE (MM/MSPLIT)   // 2048

// rescue-set margin: ~10 sigma of (bf16-dot noise sigma~7e-4 + 11-bit key quant ~2e-3).
#define EPS_KEY 0.02f

// ws layout (4-byte units): RM (NM f32) | CK (NQ*NC u32 packed keys) | ENCP (NQ*DD bf16)
#define WS_RM 0
#define WS_CK (WS_RM + NM)
#define WS_ENCP (WS_CK + NQ*NC)

typedef short bf16x8 __attribute__((ext_vector_type(8)));
typedef float f32x16 __attribute__((ext_vector_type(16)));

__device__ __forceinline__ ushort f2bf(float f) {
  unsigned u = __builtin_bit_cast(unsigned, f);
  unsigned r = u + 0x7FFFu + ((u >> 16) & 1u);   // RNE
  return (ushort)(r >> 16);
}

// single-instruction 3-input median (sorted-insert workhorse)
__device__ __forceinline__ unsigned med3u(unsigned a, unsigned b, unsigned c) {
  unsigned d;
  asm("v_med3_u32 %0, %1, %2, %3" : "=v"(d) : "v"(a), "v"(b), "v"(c));
  return d;
}

// key = (bits(v) & 0xFFFFF800) | idx  in ONE VOP3 (mask lives in an SGPR)
__device__ __forceinline__ unsigned mkkey(float v, unsigned idx) {
  unsigned d;
  asm("v_and_or_b32 %0, %1, %2, %3" : "=v"(d)
      : "v"(__builtin_bit_cast(unsigned, v)), "s"(0xFFFFF800u), "v"(idx));
  return d;
}

// sorted-desc top-5 insert via med3 identity: new[s] = med3(k, old[s-1], old[s]).
__device__ __forceinline__ void ins5(unsigned* bk, unsigned k) {
  bk[4] = med3u(k, bk[3], bk[4]);
  bk[3] = med3u(k, bk[2], bk[3]);
  bk[2] = med3u(k, bk[1], bk[2]);
  bk[1] = med3u(k, bk[0], bk[1]);
  bk[0] = (bk[0] > k) ? bk[0] : k;
}

#define CS(i, j) { const unsigned hi = (L[i] > L[j]) ? L[i] : L[j]; \
                   const unsigned lo = (L[i] > L[j]) ? L[j] : L[i]; \
                   L[i] = hi; L[j] = lo; }

// merge two sorted-desc 8-lists -> top-8 sorted desc (bitonic)
__device__ __forceinline__ void mrg8(unsigned* a, const unsigned* b) {
  unsigned L[8];
  #pragma unroll
  for (int i = 0; i < 8; ++i) L[i] = (a[i] > b[7 - i]) ? a[i] : b[7 - i];
  CS(0,4) CS(1,5) CS(2,6) CS(3,7)
  CS(0,2) CS(1,3) CS(4,6) CS(5,7)
  CS(0,1) CS(2,3) CS(4,5) CS(6,7)
  #pragma unroll
  for (int i = 0; i < 8; ++i) a[i] = L[i];
}

// ---------------- kernel 1: fused pack of enc (raw) + mem (normalized) ----------------
#define LDSW 516
__global__ __launch_bounds__(256) void k_prep2(const float* __restrict__ enc,
                                               const float* __restrict__ mem,
                                               ushort* __restrict__ encP,
                                               ushort* __restrict__ memP,
                                               float* __restrict__ rmOut) {
  __shared__ float st[32 * LDSW];
  __shared__ float rs_s[32];
  const int blk = blockIdx.x;
  const bool isenc = blk < (NQ / 32);
  const int tile = isenc ? blk : blk - NQ / 32;
  const float* src = isenc ? enc : mem;
  ushort* dstP = isenc ? encP : memP;
  const int tid = threadIdx.x;
  const float* sB = src + (size_t)tile * 32 * DD;

  #pragma unroll
  for (int i = 0; i < 16; ++i) {
    const int idx = tid + i * 256;
    const int row = idx >> 7, c4 = idx & 127;
    *(float4*)&st[row * LDSW + c4 * 4] = *(const float4*)&sB[(size_t)row * DD + c4 * 4];
  }
  __syncthreads();

  if (!isenc) {
    const int row = tid >> 3, seg = tid & 7;
    float ss = 0.0f;
    #pragma unroll
    for (int i = 0; i < 16; ++i) {
      const float4 x = *(const float4*)&st[row * LDSW + seg * 64 + i * 4];
      ss += x.x*x.x + x.y*x.y + x.z*x.z + x.w*x.w;
    }
    #pragma unroll
    for (int m = 1; m < 8; m <<= 1) ss += __shfl_xor(ss, m, 64);
    if (seg == 0) {
      const float rn = 1.0f / fmaxf(sqrtf(ss), 1e-12f);
      rs_s[row] = rn;
      rmOut[tile * 32 + row] = rn;
    }
    __syncthreads();
  }

  #pragma unroll
  for (int i = 0; i < 8; ++i) {
    const int slot = tid + i * 256;
    const int kt = slot >> 6, l = slot & 63;
    const int row = l & 31;
    const int k0 = kt * 16 + (l >> 5) * 8;
    const float sc = isenc ? 1.0f : rs_s[row];
    const float4 x0 = *(const float4*)&st[row * LDSW + k0];
    const float4 x1 = *(const float4*)&st[row * LDSW + k0 + 4];
    uint4 o;
    o.x = (unsigned)f2bf(x0.x * sc) | ((unsigned)f2bf(x0.y * sc) << 16);
    o.y = (unsigned)f2bf(x0.z * sc) | ((unsigned)f2bf(x0.w * sc) << 16);
    o.z = (unsigned)f2bf(x1.x * sc) | ((unsigned)f2bf(x1.y * sc) << 16);
    o.w = (unsigned)f2bf(x1.z * sc) | ((unsigned)f2bf(x1.w * sc) << 16);
    ((uint4*)dstP)[(size_t)tile * 2048 + slot] = o;
  }
}

// ---------------- kernel 2: 32x32x16 MFMA screen (proven R18/R19 body) ----------------
// grid 512; batch-per-XCD mapping (XCD x = batch x -> A stream L2-resident).
// block 512 thr = 8 waves; free-running; 64 KB LDS (2 blocks/CU); 60 VGPR + 64 AGPR.
// acc init 0 (never scalar-cast-splat nonzero ext-vector!); +28 bias applied at insert.
// Key: bits(acc+28)&~0x7FF | (2047 - m_in_split)  (monotone, tie -> smaller m).
__global__ __launch_bounds__(512, 4) void k_screen(const ushort* __restrict__ encP,
                                                   const ushort* __restrict__ memP,
                                                   unsigned* __restrict__ wsck) {
  __shared__ uint4 ebuf[4096];                   // 64 KB: 2 enc tiles; reused for merge lists
  unsigned* ml = (unsigned*)ebuf;
  const int tid = threadIdx.x;
  const int l = tid & 63;
  const int w = tid >> 6;                        // 0..7
  const int ord = blockIdx.x;
  const int x = ord & 7;                         // XCD id (round-robin dispatch heuristic)
  const int j = ord >> 3;                        // 0..63 within XCD
  const int qt = x * 32 + (j >> 1);              // qt in batch x  (qt>>5 == x)
  const int split = j & 1;
  const int qbase = qt * 64;
  const int atile0 = x * (MM / 32) + split * (MRANGE / 32);

  {
    const uint4* src = (const uint4*)encP + (size_t)(qt * 2) * 2048;
    #pragma unroll
    for (int i = 0; i < 8; ++i) ebuf[tid + i * 512] = src[tid + i * 512];
  }
  __syncthreads();

  unsigned tv[2][TOPS];
  #pragma unroll
  for (int qs = 0; qs < 2; ++qs)
    #pragma unroll
    for (int s = 0; s < TOPS; ++s) tv[qs][s] = 0u;

  #pragma unroll 1
  for (int t = 0; t < 4; ++t) {
    unsigned bk[2][5];
    #pragma unroll
    for (int qs = 0; qs < 2; ++qs)
      #pragma unroll
      for (int s = 0; s < 5; ++s) bk[qs][s] = 0u;

    f32x16 acc00 = (f32x16)(0.0f), acc01 = (f32x16)(0.0f);
    f32x16 acc10 = (f32x16)(0.0f), acc11 = (f32x16)(0.0f);
    const ushort* aT = memP + (size_t)(atile0 + t * 16 + w * 2) * 16384 + (size_t)l * 8;

    __builtin_amdgcn_s_setprio(1);
    #pragma unroll 2
    for (int kc = 0; kc < 32; ++kc) {
      const bf16x8 a0 = *(const bf16x8*)(aT + kc * 512);
      const bf16x8 a1 = *(const bf16x8*)(aT + 16384 + kc * 512);
      const bf16x8 b0 = *(const bf16x8*)&ebuf[kc * 64 + l];
      const bf16x8 b1 = *(const bf16x8*)&ebuf[2048 + kc * 64 + l];
      acc00 = __builtin_amdgcn_mfma_f32_32x32x16_bf16(a0, b0, acc00, 0, 0, 0);
      acc01 = __builtin_amdgcn_mfma_f32_32x32x16_bf16(a0, b1, acc01, 0, 0, 0);
      acc10 = __builtin_amdgcn_mfma_f32_32x32x16_bf16(a1, b0, acc10, 0, 0, 0);
      acc11 = __builtin_amdgcn_mfma_f32_32x32x16_bf16(a1, b1, acc11, 0, 0, 0);
    }
    __builtin_amdgcn_s_setprio(0);

    const unsigned ib0 = 2047u - (unsigned)(t * 512 + w * 64 + 4 * (l >> 5));
    #pragma unroll
    for (int r = 0; r < 16; ++r) {
      const unsigned idx = ib0 - (unsigned)((r & 3) + 8 * (r >> 2));
      ins5(bk[0], mkkey(acc00[r] + 28.0f, idx));
      ins5(bk[1], mkkey(acc01[r] + 28.0f, idx));
      ins5(bk[0], mkkey(acc10[r] + 28.0f, idx - 32u));
      ins5(bk[1], mkkey(acc11[r] + 28.0f, idx - 32u));
    }

    #pragma unroll
    for (int qs = 0; qs < 2; ++qs) {
      const unsigned bb[8] = {bk[qs][0], bk[qs][1], bk[qs][2], bk[qs][3], bk[qs][4],
                              0u, 0u, 0u};
      mrg8(tv[qs], bb);
    }
  }

  // merge lane-halves (l <-> l+32): both halves end with the full per-q list
  #pragma unroll
  for (int qs = 0; qs < 2; ++qs) {
    unsigned ov[TOPS];
    #pragma unroll
    for (int s = 0; s < TOPS; ++s) ov[s] = (unsigned)__shfl_xor((int)tv[qs][s], 32, 64);
    mrg8(tv[qs], ov);
  }

  __syncthreads();                               // all ebuf reads done; reuse LDS for lists
  if (w > 0 && l < 32) {
    #pragma unroll
    for (int qs = 0; qs < 2; ++qs)
      #pragma unroll
      for (int s = 0; s < TOPS; ++s)
        ml[((w - 1) * 64 + qs * 32 + l) * 8 + s] = tv[qs][s];
  }
  __syncthreads();
  if (w == 0) {
    #pragma unroll
    for (int pp = 0; pp < 7; ++pp) {
      #pragma unroll
      for (int qs = 0; qs < 2; ++qs) {
        unsigned ov[TOPS];
        #pragma unroll
        for (int s = 0; s < TOPS; ++s) ov[s] = ml[(pp * 64 + qs * 32 + (l & 31)) * 8 + s];
        mrg8(tv[qs], ov);
      }
    }
    if (l < 32) {
      #pragma unroll
      for (int qs = 0; qs < 2; ++qs) {
        const int q = qbase + qs * 32 + l;
        #pragma unroll
        for (int s = 0; s < TOPS; ++s)
          wsck[q * NC + split * TOPS + s] = tv[qs][s];   // packed key
      }
    }
  }
}

// ---------------- kernel 3: certified rescue-set fp64 rescore (R19 strided body) ----------------
// With EPS_KEY=0.02 the rescue set prunes to T~6-7; phase 2 is iteration-starved (~1.6
// iters/wave) so the simple strided loop is optimal (batched variants regressed: R14, R20).
__global__ __launch_bounds__(256) void k_out(const float* __restrict__ enc,
                                             const float* __restrict__ mem,
                                             const float* __restrict__ wsf,
                                             const unsigned* __restrict__ wsck,
                                             float* __restrict__ out) {
  __shared__ double sc_s[NC];
  __shared__ int cm_s[NC];
  __shared__ int lst_s[NC];
  __shared__ int T_s;
  __shared__ int sel_s[TOPK];
  const int ord = blockIdx.x;
  const int row = (ord & 7) * 2048 + (ord >> 3);   // bijective: XCD x <- batch x
  const int tid = threadIdx.x;
  const int lane = tid & 63;
  const int w = tid >> 6;
  const int b = row >> 11;
  const float* er = enc + (size_t)row * DD;
  const float* mb = mem + (size_t)b * MM * DD;

  // --- phase 1: build rescue list from packed keys (wave 0) ---
  if (w == 0) {
    const unsigned my = (lane < NC) ? wsck[row * NC + lane] : 0u;
    int rank = 0;
    #pragma unroll
    for (int e2 = 0; e2 < NC; ++e2) {
      const unsigned o = (unsigned)__shfl((int)my, e2, 64);
      rank += (o > my) ? 1 : 0;
    }
    unsigned c5 = (rank == 4) ? my : 0u;
    #pragma unroll
    for (int off = 1; off < 16; off <<= 1)
      c5 |= (unsigned)__shfl_xor((int)c5, off, 64);
    const float kf5 = __builtin_bit_cast(float, c5 & 0xFFFFF800u);
    const float kfm = __builtin_bit_cast(float, my & 0xFFFFF800u);
    const bool flag = (lane < NC) && (kfm >= kf5 - EPS_KEY);
    const unsigned long long bmask = __ballot(flag);
    const unsigned lowm = (unsigned)bmask & 0xFFFFu;
    if (flag) {
      const int pos = __popc(lowm & ((1u << lane) - 1u));
      const int split = lane >> 3;               // slots 0-7 split0, 8-15 split1
      lst_s[pos] = split * MRANGE + 2047 - (int)(my & 0x7FFu);
    }
    if (lane == 0) T_s = __popc(lowm);
    if (lane < NC) { sc_s[lane] = -1.0e300; cm_s[lane] = 0x7fff0000 + lane; }
  }
  __syncthreads();
  const int T = T_s;

  // --- phase 2: strided fp64 rescore of rescue set ---
  const int d0 = lane * 8;
  const float4 e0 = *(const float4*)(er + d0);
  const float4 e1 = *(const float4*)(er + d0 + 4);
  const double ed0 = e0.x, ed1 = e0.y, ed2 = e0.z, ed3 = e0.w;
  const double ed4 = e1.x, ed5 = e1.y, ed6 = e1.z, ed7 = e1.w;

  for (int j = w; j < T; j += 4) {
    const int cm = lst_s[j];
    const float* mr = mb + (size_t)cm * DD + d0;
    const float4 x0 = *(const float4*)mr;
    const float4 x1 = *(const float4*)(mr + 4);
    double t = ed0 * (double)x0.x;
    t = fma(ed1, (double)x0.y, t); t = fma(ed2, (double)x0.z, t);
    t = fma(ed3, (double)x0.w, t); t = fma(ed4, (double)x1.x, t);
    t = fma(ed5, (double)x1.y, t); t = fma(ed6, (double)x1.z, t);
    t = fma(ed7, (double)x1.w, t);
    #pragma unroll
    for (int off = 1; off < 64; off <<= 1) t += __shfl_xor(t, off, 64);
    if (lane == 0) {
      sc_s[j] = t * (double)wsf[WS_RM + b * MM + cm];
      cm_s[j] = cm;
    }
  }
  __syncthreads();

  // --- phase 3: wave 0 ranks rescued scores by (value desc, index asc) ---
  if (w == 0) {
    const int e = lane & 15;
    const double mk = sc_s[e];
    const int mi = cm_s[e];
    int rank = 0;
    #pragma unroll
    for (int e2 = 0; e2 < NC; ++e2) {
      const double k2 = sc_s[e2];
      const int i2 = cm_s[e2];
      rank += ((k2 > mk) || (k2 == mk && i2 < mi)) ? 1 : 0;
    }
    if (lane < NC && rank < TOPK) sel_s[rank] = mi;
  }
  __syncthreads();

  // --- phase 4: gather + mean + add (2 dims/thread) ---
  const int sel0 = sel_s[0], sel1 = sel_s[1], sel2 = sel_s[2],
            sel3 = sel_s[3], sel4 = sel_s[4];
  const int d = tid * 2;
  const float2 ev = *(const float2*)(er + d);
  const float2 x0 = *(const float2*)(mb + (size_t)sel0 * DD + d);
  const float2 x1 = *(const float2*)(mb + (size_t)sel1 * DD + d);
  const float2 x2 = *(const float2*)(mb + (size_t)sel2 * DD + d);
  const float2 x3 = *(const float2*)(mb + (size_t)sel3 * DD + d);
  const float2 x4 = *(const float2*)(mb + (size_t)sel4 * DD + d);
  float2 o;
  o.x = ev.x + (x0.x + x1.x + x2.x + x3.x + x4.x) / 5.0f;
  o.y = ev.y + (x0.y + x1.y + x2.y + x3.y + x4.y) / 5.0f;
  *(float2*)(out + (size_t)row * DD + d) = o;
}

extern "C" void kernel_launch(void* const* d_in, const int* in_sizes, int n_in,
                              void* d_out, int out_size, void* d_ws, size_t ws_size,
                              hipStream_t stream) {
  (void)in_sizes; (void)n_in; (void)out_size; (void)ws_size;
  const float* enc = (const float*)d_in[0];
  const float* mem = (const float*)d_in[1];
  float* out = (float*)d_out;
  float* wsf = (float*)d_ws;
  unsigned* wsck = (unsigned*)d_ws + WS_CK;
  ushort* encP = (ushort*)(wsf + WS_ENCP);
  ushort* memP = (ushort*)d_out;   // NM*DD bf16 == out bytes exactly; k_out overwrites

  // 1) fused pack: enc (raw) + mem (row-normalized) into 32x32x16 MFMA operand layout
  k_prep2<<<dim3(NQ / 32 + NM / 32), dim3(256), 0, stream>>>(enc, mem, encP, memP,
                                                             wsf + WS_RM);

  // 2) MFMA screening: per (row, M/2-split) top-8 packed keys (batch-per-XCD mapping)
  k_screen<<<dim3(512), dim3(512), 0, stream>>>(encP, memP, wsck);

  // 3) certified rescue-set fp64 rescore, exact top-5, gather, mean, add
  k_out<<<dim3(NQ), dim3(256), 0, stream>>>(enc, mem, wsf, wsck, out);
}